// Round 11
// baseline (884.564 us; speedup 1.0000x reference)
//
#include <hip/hip_runtime.h>

typedef float f32x4  __attribute__((ext_vector_type(4)));
typedef int   i32x4  __attribute__((ext_vector_type(4)));
typedef char  s8x16  __attribute__((ext_vector_type(16)));

#define GAS __attribute__((address_space(1)))
#define LAS __attribute__((address_space(3)))
#define SBAR __builtin_amdgcn_sched_barrier(0)

constexpr int M = 8192;       // B*S
constexpr int N = 16384;      // D_OUT
constexpr int K = 4096;       // D_IN
constexpr long long NX = (long long)M * K;   // 33,554,432
constexpr long long NW = (long long)N * K;   // 67,108,864
constexpr int NPART = 2048;

constexpr int BKB  = 64;              // K-bytes per tile
constexpr int NTT  = K / BKB;         // 64 K-tiles
constexpr int ABY  = 128 * BKB;       // 8192
constexpr int BBY  = 256 * BKB;       // 16384
constexpr int BUFB = ABY + BBY;       // 24576; ring of 3 = 72 KiB

// ---------------- reductions ----------------

__global__ void reduce_absmax_kernel(const float* __restrict__ x,
                                     unsigned* __restrict__ gmax, int n4) {
  float m = 0.f;
  int stride = gridDim.x * blockDim.x;
  for (int i = blockIdx.x * blockDim.x + threadIdx.x; i < n4; i += stride) {
    f32x4 v = *(const f32x4*)(x + (size_t)i * 4);
    m = fmaxf(m, fmaxf(fmaxf(fabsf(v[0]), fabsf(v[1])),
                       fmaxf(fabsf(v[2]), fabsf(v[3]))));
  }
#pragma unroll
  for (int off = 32; off > 0; off >>= 1) m = fmaxf(m, __shfl_down(m, off));
  __shared__ float sm[4];
  int lane = threadIdx.x & 63, wid = threadIdx.x >> 6;
  if (lane == 0) sm[wid] = m;
  __syncthreads();
  if (threadIdx.x == 0) {
    m = fmaxf(fmaxf(sm[0], sm[1]), fmaxf(sm[2], sm[3]));
    atomicMax(gmax, __float_as_uint(m));  // |x| >= 0: bit-order == float-order
  }
}

__global__ void reduce_abssum_kernel(const float* __restrict__ w,
                                     float* __restrict__ partials, int n4) {
  float s = 0.f;
  int stride = gridDim.x * blockDim.x;
  for (int i = blockIdx.x * blockDim.x + threadIdx.x; i < n4; i += stride) {
    f32x4 v = *(const f32x4*)(w + (size_t)i * 4);
    s += fabsf(v[0]) + fabsf(v[1]) + fabsf(v[2]) + fabsf(v[3]);
  }
#pragma unroll
  for (int off = 32; off > 0; off >>= 1) s += __shfl_down(s, off);
  __shared__ float sm[4];
  int lane = threadIdx.x & 63, wid = threadIdx.x >> 6;
  if (lane == 0) sm[wid] = s;
  __syncthreads();
  if (threadIdx.x == 0) partials[blockIdx.x] = (sm[0] + sm[1]) + (sm[2] + sm[3]);
}

__global__ void finalize_kernel(const unsigned* __restrict__ gbits,
                                const float* __restrict__ partials,
                                float* __restrict__ params) {
  __shared__ double sd[256];
  double s = 0.0;
  for (int i = threadIdx.x; i < NPART; i += 256) s += (double)partials[i];
  sd[threadIdx.x] = s;
  __syncthreads();
  for (int h = 128; h > 0; h >>= 1) {
    if (threadIdx.x < h) sd[threadIdx.x] += sd[threadIdx.x + h];
    __syncthreads();
  }
  if (threadIdx.x == 0) {
    float beta  = fmaxf((float)(sd[0] / (double)NW), 1e-5f);
    float gamma = fmaxf(__uint_as_float(gbits[0]), 1e-5f);
    params[0] = 128.0f / gamma;          // activation scale (q/gamma)
    params[1] = beta;                    // weight divisor
    params[2] = beta * gamma / 128.0f;   // output rescale
  }
}

// ---------------- quantization (int8 outputs, linear layouts) ----------------

__global__ void quant_x_kernel(const float* __restrict__ x,
                               char* __restrict__ xq,
                               const float* __restrict__ params, int n16) {
  float s = params[0];
  int stride = gridDim.x * blockDim.x;
  for (int i = blockIdx.x * blockDim.x + threadIdx.x; i < n16; i += stride) {
    const f32x4* p = (const f32x4*)(x + (size_t)i * 16);
    s8x16 o;
#pragma unroll
    for (int v = 0; v < 4; ++v) {
      f32x4 t = p[v];
#pragma unroll
      for (int k = 0; k < 4; ++k) {
        float r = fminf(fmaxf(rintf(t[k] * s), -128.f), 127.f);
        o[v * 4 + k] = (char)(int)r;
      }
    }
    *(s8x16*)(xq + (size_t)i * 16) = o;
  }
}

__global__ void quant_w_kernel(const float* __restrict__ w,
                               char* __restrict__ wq,
                               const float* __restrict__ params, int n16) {
  float beta = params[1];
  int stride = gridDim.x * blockDim.x;
  for (int i = blockIdx.x * blockDim.x + threadIdx.x; i < n16; i += stride) {
    const f32x4* p = (const f32x4*)(w + (size_t)i * 16);
    s8x16 o;
#pragma unroll
    for (int v = 0; v < 4; ++v) {
      f32x4 t = p[v];
#pragma unroll
      for (int k = 0; k < 4; ++k) {
        // round_clip(|w|/beta, -1, 1): nonneg -> {0,1}; IEEE div matches ref rounding
        o[v * 4 + k] = (rintf(fabsf(t[k]) / beta) >= 1.0f) ? (char)1 : (char)0;
      }
    }
    *(s8x16*)(wq + (size_t)i * 16) = o;
  }
}

// ---------------- GEMM: 128x256 tile, 4 waves x (64x128), BK=64B, 3-ring
// C[m][n] = sum_k A[m][k] * B[n][k]  (B row-major [N][K] == B^T input)
// The lever vs rounds 5-10: ds_reads per MFMA = 12/32 = 0.375 (long-thin
// 64x128 waves) instead of 8/16 = 0.5 -> LDS-pipe demand (~1152 cyc/CU-slot)
// < matrix-pipe demand (~1242) for the first time; matrix pipe binds.
// Skeleton = round 6 (validated): 3-ring, counted vmcnt(6) depth-2 prefetch,
// ONE barrier/K-tile, 2 blocks/CU (72KB LDS) for decorrelated overlap.
// Swizzle = round 4's measured-conflict-free 2-bit slot XOR (16-row-span
// reads): LDS[row][s] = global[row][s ^ ((row>>1)&3)], linear LDS dest.

__global__ __launch_bounds__(256, 2) void gemm_kernel(
    const char* __restrict__ A,   // xq int8 [M][K]
    const char* __restrict__ B,   // wq int8 [N][K]
    float* __restrict__ C,        // [M][N] fp32
    const float* __restrict__ params) {
  __shared__ __align__(16) char lds[3 * BUFB];   // 72 KiB

  const int tid  = threadIdx.x;
  const int lane = tid & 63;
  const int wid  = tid >> 6;
  const int wm = wid >> 1, wn = wid & 1;      // 2x2 waves, each 64x128
  const int r16 = lane & 15, q4 = lane >> 4;

  // XCD swizzle (4096 % 8 == 0): each XCD chunk walks m fastest so its 64
  // consecutive blocks share one B panel (1 MB) in that XCD's L2.
  const int wg = (blockIdx.x & 7) * 512 + (blockIdx.x >> 3);
  const int m0 = (wg & 63) * 128;
  const int n0 = (wg >> 6) * 256;

  // ---- staging: per instr 256 threads x 16B = 64 rows x 64B.
  // thread -> row (tid>>2), LDS slot tid&3 (linear dest), global slot
  // (tid&3)^((row>>1)&3); row>>1&3 == (tid>>3)&3.
  const int csw = ((tid & 3) ^ ((tid >> 3) & 3)) * 16;
  const char* gA = A + (size_t)(m0 + (tid >> 2)) * K + csw;
  const char* gB = B + (size_t)(n0 + (tid >> 2)) * K + csw;
  const int dst = tid * 16;

  auto stage = [&](int t, int bo) {
    char* L = lds + bo;
    const size_t ko = (size_t)t * BKB;
    __builtin_amdgcn_global_load_lds((const GAS void*)(gA + ko),                (LAS void*)(L + dst),         16, 0, 0);
    __builtin_amdgcn_global_load_lds((const GAS void*)(gA + ko + (size_t)64*K), (LAS void*)(L + 4096 + dst),  16, 0, 0);
    __builtin_amdgcn_global_load_lds((const GAS void*)(gB + ko),                (LAS void*)(L + ABY + dst),          16, 0, 0);
    __builtin_amdgcn_global_load_lds((const GAS void*)(gB + ko + (size_t)64*K), (LAS void*)(L + ABY + 4096 + dst),   16, 0, 0);
    __builtin_amdgcn_global_load_lds((const GAS void*)(gB + ko + (size_t)128*K),(LAS void*)(L + ABY + 8192 + dst),   16, 0, 0);
    __builtin_amdgcn_global_load_lds((const GAS void*)(gB + ko + (size_t)192*K),(LAS void*)(L + ABY + 12288 + dst),  16, 0, 0);
  };

  // ---- fragment reads (round-4 pattern, measured conflict-free):
  // global slot q4 of row -> LDS slot q4^((row>>1)&3); row = base16 + r16.
  const int rsw = ((q4 ^ ((r16 >> 1) & 3)) * 16);
  int aoff[4], boff[8];
#pragma unroll
  for (int fm = 0; fm < 4; ++fm)
    aoff[fm] = (wm * 64 + fm * 16 + r16) * BKB + rsw;
#pragma unroll
  for (int fn = 0; fn < 8; ++fn)
    boff[fn] = ABY + (wn * 128 + fn * 16 + r16) * BKB + rsw;

  i32x4 acc[4][8] = {};

  auto compute = [&](int bo) {
    const char* buf = lds + bo;
    i32x4 af[4], bf[8];
#pragma unroll
    for (int fm = 0; fm < 4; ++fm) af[fm] = *(const i32x4*)(buf + aoff[fm]);
#pragma unroll
    for (int fn = 0; fn < 8; ++fn) bf[fn] = *(const i32x4*)(buf + boff[fn]);
    __builtin_amdgcn_s_setprio(1);
#pragma unroll
    for (int fn = 0; fn < 8; ++fn)
#pragma unroll
      for (int fm = 0; fm < 4; ++fm)
        acc[fm][fn] = __builtin_amdgcn_mfma_i32_16x16x64_i8(af[fm], bf[fn], acc[fm][fn], 0, 0, 0);
    __builtin_amdgcn_s_setprio(0);
  };

  // prologue: tiles 0,1 staged (12 loads in flight)
  stage(0, 0);
  stage(1, BUFB);

  int cb = 0, sb = 2 * BUFB;
  for (int t = 0; t < NTT; ++t) {
    // outstanding at top: tiles t, t+1 (12 loads) for t<NTT-1; else 6.
    // in-order retirement: vmcnt(6) certifies tile t resident.
    if (t < NTT - 1) {
      asm volatile("s_waitcnt vmcnt(6)" ::: "memory");
    } else {
      asm volatile("s_waitcnt vmcnt(0)" ::: "memory");
    }
    SBAR;
    // barrier: all waves' tile-t shares resident AND all waves done reading
    // tile t-1 (ds_reads retired before their MFMAs which precede arrival),
    // so stage(t+2) overwriting buf[t-1] below is race-free.
    __builtin_amdgcn_s_barrier();
    SBAR;
    if (t + 2 < NTT) stage(t + 2, sb);
    compute(cb);
    cb = (cb == 2 * BUFB) ? 0 : cb + BUFB;
    sb = (sb == 2 * BUFB) ? 0 : sb + BUFB;
  }

  // epilogue: C/D layout (m89-verified): col = lane&15, row = (lane>>4)*4+reg
  const float sc = params[2];
  const int crow = m0 + wm * 64 + q4 * 4;
  const int ccol = n0 + wn * 128 + r16;
#pragma unroll
  for (int fm = 0; fm < 4; ++fm)
#pragma unroll
    for (int fn = 0; fn < 8; ++fn)
#pragma unroll
      for (int r = 0; r < 4; ++r)
        C[(size_t)(crow + fm * 16 + r) * N + (ccol + fn * 16)] = (float)acc[fm][fn][r] * sc;
}

// ---------------- launch ----------------

extern "C" void kernel_launch(void* const* d_in, const int* in_sizes, int n_in,
                              void* d_out, int out_size, void* d_ws, size_t ws_size,
                              hipStream_t stream) {
  const float* x = (const float*)d_in[0];
  const float* w = (const float*)d_in[1];
  float* out = (float*)d_out;
  char* ws = (char*)d_ws;

  unsigned* gamma_bits = (unsigned*)ws;            // 4 B
  float*    params     = (float*)(ws + 16);        // 3 floats
  float*    partials   = (float*)(ws + 256);       // 2048 floats
  char*     xq = ws + 16384;                       // 33,554,432 B
  char*     wq = ws + 16384 + (size_t)NX;          // 67,108,864 B

  hipMemsetAsync(ws, 0, 256, stream);  // zero gamma accumulator each call

  reduce_absmax_kernel<<<NPART, 256, 0, stream>>>(x, gamma_bits, (int)(NX / 4));
  reduce_abssum_kernel<<<NPART, 256, 0, stream>>>(w, partials, (int)(NW / 4));
  finalize_kernel<<<1, 256, 0, stream>>>(gamma_bits, partials, params);
  quant_x_kernel<<<2048, 256, 0, stream>>>(x, xq, params, (int)(NX / 16));
  quant_w_kernel<<<2048, 256, 0, stream>>>(w, wq, params, (int)(NW / 16));

  gemm_kernel<<<4096, 256, 0, stream>>>(xq, wq, out, params);
}

// Round 12
// 748.311 us; speedup vs baseline: 1.1821x; 1.1821x over previous
//
#include <hip/hip_runtime.h>

typedef float f32x4  __attribute__((ext_vector_type(4)));
typedef int   i32x4  __attribute__((ext_vector_type(4)));
typedef char  s8x16  __attribute__((ext_vector_type(16)));

#define GAS __attribute__((address_space(1)))
#define LAS __attribute__((address_space(3)))
#define SBAR __builtin_amdgcn_sched_barrier(0)

constexpr int M = 8192;       // B*S
constexpr int N = 16384;      // D_OUT
constexpr int K = 4096;       // D_IN
constexpr long long NX = (long long)M * K;   // 33,554,432
constexpr long long NW = (long long)N * K;   // 67,108,864
constexpr int NPART = 2048;

constexpr int BKB    = 64;               // K-bytes per tile (i8)
constexpr int NTT    = K / BKB;          // 64 K-tiles
constexpr int ABYTES = 256 * BKB;        // 16384
constexpr int BBYTES = 128 * BKB;        // 8192
constexpr int BUFB   = ABYTES + BBYTES;  // 24576

// ---------------- merged reductions (one launch, two jobs) ----------------
// Blocks 0..2047: absmax over x  — order-free (max), any tree OK.
// Blocks 2048..4095: abssum over w — base/stride/tree BIT-IDENTICAL to the
// validated 2048-block version (beta must not change: boundary weights at
// |w|/beta ~ 0.5 flip otherwise).

__global__ void reduce_both_kernel(const float* __restrict__ x,
                                   const float* __restrict__ w,
                                   unsigned* __restrict__ gmax,
                                   float* __restrict__ partials) {
  const int tid = threadIdx.x;
  const int lane = tid & 63, wwid = tid >> 6;
  __shared__ float sm[4];
  if ((int)blockIdx.x < NPART) {
    float m = 0.f;
    const int n4 = (int)(NX / 4);
    for (int i = blockIdx.x * 256 + tid; i < n4; i += NPART * 256) {
      f32x4 v = *(const f32x4*)(x + (size_t)i * 4);
      m = fmaxf(m, fmaxf(fmaxf(fabsf(v[0]), fabsf(v[1])),
                         fmaxf(fabsf(v[2]), fabsf(v[3]))));
    }
#pragma unroll
    for (int off = 32; off > 0; off >>= 1) m = fmaxf(m, __shfl_down(m, off));
    if (lane == 0) sm[wwid] = m;
    __syncthreads();
    if (tid == 0) {
      m = fmaxf(fmaxf(sm[0], sm[1]), fmaxf(sm[2], sm[3]));
      atomicMax(gmax, __float_as_uint(m));  // |x| >= 0: bit-order == float-order
    }
  } else {
    const int bb = blockIdx.x - NPART;
    float s = 0.f;
    const int n4 = (int)(NW / 4);
    for (int i = bb * 256 + tid; i < n4; i += NPART * 256) {
      f32x4 v = *(const f32x4*)(w + (size_t)i * 4);
      s += fabsf(v[0]) + fabsf(v[1]) + fabsf(v[2]) + fabsf(v[3]);
    }
#pragma unroll
    for (int off = 32; off > 0; off >>= 1) s += __shfl_down(s, off);
    if (lane == 0) sm[wwid] = s;
    __syncthreads();
    if (tid == 0) partials[bb] = (sm[0] + sm[1]) + (sm[2] + sm[3]);
  }
}

__global__ void finalize_kernel(const unsigned* __restrict__ gbits,
                                const float* __restrict__ partials,
                                float* __restrict__ params) {
  __shared__ double sd[256];
  double s = 0.0;
  for (int i = threadIdx.x; i < NPART; i += 256) s += (double)partials[i];
  sd[threadIdx.x] = s;
  __syncthreads();
  for (int h = 128; h > 0; h >>= 1) {
    if (threadIdx.x < h) sd[threadIdx.x] += sd[threadIdx.x + h];
    __syncthreads();
  }
  if (threadIdx.x == 0) {
    float beta  = fmaxf((float)(sd[0] / (double)NW), 1e-5f);
    float gamma = fmaxf(__uint_as_float(gbits[0]), 1e-5f);
    params[0] = 128.0f / gamma;          // activation scale (q/gamma)
    params[1] = beta;                    // weight divisor
    params[2] = beta * gamma / 128.0f;   // output rescale
  }
}

// ---------------- merged quantization (elementwise, order-free) ----------------
// Blocks 0..2047: x -> int8.  Blocks 2048..6143: w -> {0,1} int8.

__global__ void quant_both_kernel(const float* __restrict__ x,
                                  const float* __restrict__ w,
                                  char* __restrict__ xq,
                                  char* __restrict__ wq,
                                  const float* __restrict__ params) {
  const int tid = threadIdx.x;
  if ((int)blockIdx.x < 2048) {
    const float s = params[0];
    const int n16 = (int)(NX / 16);
    for (int i = blockIdx.x * 256 + tid; i < n16; i += 2048 * 256) {
      const f32x4* p = (const f32x4*)(x + (size_t)i * 16);
      s8x16 o;
#pragma unroll
      for (int v = 0; v < 4; ++v) {
        f32x4 t = p[v];
#pragma unroll
        for (int k = 0; k < 4; ++k) {
          float r = fminf(fmaxf(rintf(t[k] * s), -128.f), 127.f);
          o[v * 4 + k] = (char)(int)r;
        }
      }
      *(s8x16*)(xq + (size_t)i * 16) = o;
    }
  } else {
    const float beta = params[1];
    const int bb = blockIdx.x - 2048;         // 4096 blocks
    const int n16 = (int)(NW / 16);
    for (int i = bb * 256 + tid; i < n16; i += 4096 * 256) {
      const f32x4* p = (const f32x4*)(w + (size_t)i * 16);
      s8x16 o;
#pragma unroll
      for (int v = 0; v < 4; ++v) {
        f32x4 t = p[v];
#pragma unroll
        for (int k = 0; k < 4; ++k) {
          // round_clip(|w|/beta, -1, 1): nonneg -> {0,1}; IEEE div matches ref
          o[v * 4 + k] = (rintf(fabsf(t[k]) / beta) >= 1.0f) ? (char)1 : (char)0;
        }
      }
      *(s8x16*)(wq + (size_t)i * 16) = o;
    }
  }
}

// ---------------- GEMM: round-6 champion, verbatim ----------------
// 256x128 tile, 8 waves x 64x64, BK=64B, 3-buf ring, 2 blocks/CU.
// Counted vmcnt(3) (tile t+1's 3 loads stay in flight), ONE barrier/K-tile.
// Swizzle slot^=(row>>1)&3 (measured conflict-free), linear LDS dest +
// swizzled global source + matching swizzled ds_read (rule #21).
// Best measured: 580 us GEMM, MfmaUtil 42.6%, conflicts 0, absmax 0.0.

__global__ __launch_bounds__(512, 4) void gemm_kernel(
    const char* __restrict__ A,   // xq int8 [M][K]
    const char* __restrict__ B,   // wq int8 [N][K]
    float* __restrict__ C,        // [M][N] fp32
    const float* __restrict__ params) {
  __shared__ __align__(16) char lds[3 * BUFB];   // 72 KiB

  const int tid  = threadIdx.x;
  const int lane = tid & 63, wid = tid >> 6;
  const int wm = wid >> 1, wn = wid & 1;          // 4x2 waves, each 64x64
  const int r16 = lane & 15, q4 = lane >> 4;

  // XCD swizzle; grid 4096 = 32 m-tiles x 128 n-tiles, m-major chunks.
  const int wg = (blockIdx.x & 7) * 512 + (blockIdx.x >> 3);
  const int m0 = (wg >> 7) * 256, n0 = (wg & 127) * 128;

  const int csw = (((lane & 3) ^ ((lane >> 3) & 3))) * 16;
  const char* gA = A + (size_t)(m0 + wid * 32 + (lane >> 2)) * K + csw;
  const char* gB = B + (size_t)(n0 + wid * 16 + (lane >> 2)) * K + csw;
  const int dA = wid * 2048 + lane * 16;
  const int dB = ABYTES + wid * 1024 + lane * 16;

  auto stage = [&](int t, int bo) {
    char* L = lds + bo;
    const char* a = gA + t * BKB;
    __builtin_amdgcn_global_load_lds((const GAS void*)a,              (LAS void*)(L + dA),        16, 0, 0);
    __builtin_amdgcn_global_load_lds((const GAS void*)(a + 16 * K),   (LAS void*)(L + dA + 1024), 16, 0, 0);
    __builtin_amdgcn_global_load_lds((const GAS void*)(gB + t * BKB), (LAS void*)(L + dB),        16, 0, 0);
  };

  int aoff[4], boff[4];
  const int rsw = ((q4 ^ ((r16 >> 1) & 3)) * 16);
#pragma unroll
  for (int i = 0; i < 4; ++i)
    aoff[i] = (wm * 64 + i * 16 + r16) * BKB + rsw;
#pragma unroll
  for (int j = 0; j < 4; ++j)
    boff[j] = ABYTES + (wn * 64 + j * 16 + r16) * BKB + rsw;

  i32x4 acc[4][4] = {};

  auto compute = [&](int bo) {
    const char* buf = lds + bo;
    i32x4 af[4], bf[4];
#pragma unroll
    for (int i = 0; i < 4; ++i) af[i] = *(const i32x4*)(buf + aoff[i]);
#pragma unroll
    for (int j = 0; j < 4; ++j) bf[j] = *(const i32x4*)(buf + boff[j]);
    __builtin_amdgcn_s_setprio(1);
#pragma unroll
    for (int i = 0; i < 4; ++i)
#pragma unroll
      for (int j = 0; j < 4; ++j)
        acc[i][j] = __builtin_amdgcn_mfma_i32_16x16x64_i8(af[i], bf[j], acc[i][j], 0, 0, 0);
    __builtin_amdgcn_s_setprio(0);
  };

  stage(0, 0);
  stage(1, BUFB);

  int cb = 0, sb = 2 * BUFB;
  for (int t = 0; t < NTT - 1; ++t) {
    // outstanding: tiles t, t+1 (6 ops); in-order retirement -> vmcnt(3)
    // certifies tile t resident (this wave's share).
    asm volatile("s_waitcnt vmcnt(3)" ::: "memory");
    SBAR;
    // barrier: all waves' tile-t shares resident AND all waves done reading
    // tile t-1 -> stage(t+2) overwriting buf[t-1] below is race-free.
    __builtin_amdgcn_s_barrier();
    SBAR;
    if (t + 2 < NTT) stage(t + 2, sb);
    compute(cb);
    cb = (cb == 2 * BUFB) ? 0 : cb + BUFB;
    sb = (sb == 2 * BUFB) ? 0 : sb + BUFB;
  }
  asm volatile("s_waitcnt vmcnt(0)" ::: "memory");
  SBAR;
  __builtin_amdgcn_s_barrier();
  SBAR;
  compute(cb);

  // epilogue: C/D layout (m89-verified): col = lane&15, row = (lane>>4)*4+reg
  const float sc = params[2];
  const int crow = m0 + wm * 64 + q4 * 4;
  const int ccol = n0 + wn * 64 + r16;
#pragma unroll
  for (int i = 0; i < 4; ++i)
#pragma unroll
    for (int j = 0; j < 4; ++j)
#pragma unroll
      for (int r = 0; r < 4; ++r)
        C[(size_t)(crow + i * 16 + r) * N + (ccol + j * 16)] = (float)acc[i][j][r] * sc;
}

// ---------------- launch ----------------

extern "C" void kernel_launch(void* const* d_in, const int* in_sizes, int n_in,
                              void* d_out, int out_size, void* d_ws, size_t ws_size,
                              hipStream_t stream) {
  const float* x = (const float*)d_in[0];
  const float* w = (const float*)d_in[1];
  float* out = (float*)d_out;
  char* ws = (char*)d_ws;

  unsigned* gamma_bits = (unsigned*)ws;            // 4 B
  float*    params     = (float*)(ws + 16);        // 3 floats
  float*    partials   = (float*)(ws + 256);       // 2048 floats
  char*     xq = ws + 16384;                       // 33,554,432 B
  char*     wq = ws + 16384 + (size_t)NX;          // 67,108,864 B

  hipMemsetAsync(ws, 0, 256, stream);  // zero gamma accumulator each call

  reduce_both_kernel<<<2 * NPART, 256, 0, stream>>>(x, w, gamma_bits, partials);
  finalize_kernel<<<1, 256, 0, stream>>>(gamma_bits, partials, params);
  quant_both_kernel<<<6144, 256, 0, stream>>>(x, w, xq, wq, params);

  gemm_kernel<<<4096, 512, 0, stream>>>(xq, wq, out, params);
}